// Round 9
// baseline (6248.475 us; speedup 1.0000x reference)
//
#include <hip/hip_runtime.h>
#include <cstdint>

typedef unsigned u32t;
typedef unsigned long long u64;
typedef float f32x4 __attribute__((ext_vector_type(4)));
typedef short s16x4 __attribute__((ext_vector_type(4)));

#define Qn   515
#define QP   520
#define Bn   256
#define Tn   512
#define OQ   516
#define EPSc 1e-16f
#define NSL  65           // real cols per block slice
#define NT   5            // 16-wide n tiles per slice
#define KT   33           // k tiles over padded k space (528/16)
#define KTA  17           // split-K first chunk
#define USTR 532          // ushorts per ustage row
#define GR   16           // groups
#define NCH  2            // chains (independent 8-row recurrences) per group
#define NBLK 8
#define RW   264          // u64 exchange words per row (bf16-pair + tag each)

// workspace layout (bytes)
#define WS_AMATH 0                            // 544*260*4 = 565,760
#define WS_INIT  565760                       // pad to 568,320
#define WS_FBUF  568320                       // 2*GR*NCH*8*RW*8 = 1,081,344
#define WS_TOTAL (WS_FBUF + 1081344)          // 1,649,664

// LDS layout (bytes)
#define L_FRAG 0
#define L_UST  (NT*KT*64*8)                   // 84,480
#define USTB   (16*USTR*2)                    // 17,024 per chain
#define LDS_TOTAL (L_UST + NCH*USTB + 16)     // 118,544 -> 1 block/CU

__device__ __forceinline__ unsigned bfbits(float x) {
    unsigned u = __builtin_bit_cast(unsigned, x);
    unsigned r = u + 0x7FFFu + ((u >> 16) & 1u);
    return r >> 16;
}
__device__ __forceinline__ float bflo(u32t w) { return __builtin_bit_cast(float, w << 16); }
__device__ __forceinline__ float bfhi(u32t w) { return __builtin_bit_cast(float, w & 0xffff0000u); }

__global__ void prep_A(const float* __restrict__ logA, unsigned* __restrict__ AMATh) {
    __shared__ float red[4];
    __shared__ float srow[Qn];
    int row = blockIdx.x, tid = threadIdx.x;
    if (row >= Qn) {
        for (int c = tid; c < 260; c += 256) AMATh[(size_t)row*260 + c] = 0u;
        return;
    }
    float mx = -1e30f;
    for (int c = tid; c < Qn; c += 256) { float x = logA[(size_t)row*Qn + c]; srow[c] = x; mx = fmaxf(mx, x); }
#pragma unroll
    for (int o = 32; o > 0; o >>= 1) mx = fmaxf(mx, __shfl_xor(mx, o));
    if ((tid & 63) == 0) red[tid >> 6] = mx;
    __syncthreads();
    mx = fmaxf(fmaxf(red[0], red[1]), fmaxf(red[2], red[3]));
    __syncthreads();
    float sm = 0.f;
    for (int c = tid; c < Qn; c += 256) sm += __expf(srow[c] - mx);
#pragma unroll
    for (int o = 32; o > 0; o >>= 1) sm += __shfl_xor(sm, o);
    if ((tid & 63) == 0) red[tid >> 6] = sm;
    __syncthreads();
    float inv = 1.f / (red[0] + red[1] + red[2] + red[3]);
    for (int c2 = tid; c2 < 260; c2 += 256) {
        int c = 2*c2;
        float v0 = (c   < Qn) ? __expf(srow[c]   - mx) * inv : 0.f;
        float v1 = (c+1 < Qn) ? __expf(srow[c+1] - mx) * inv : 0.f;
        AMATh[(size_t)row*260 + c2] = bfbits(v0) | (bfbits(v1) << 16);
    }
}

__global__ void prep_init(const float* __restrict__ il, float* __restrict__ INITD) {
    __shared__ float red[4];
    __shared__ float srow[Qn];
    int tid = threadIdx.x;
    float mx = -1e30f;
    for (int c = tid; c < Qn; c += 256) { float x = il[c]; srow[c] = x; mx = fmaxf(mx, x); }
#pragma unroll
    for (int o = 32; o > 0; o >>= 1) mx = fmaxf(mx, __shfl_xor(mx, o));
    if ((tid & 63) == 0) red[tid >> 6] = mx;
    __syncthreads();
    mx = fmaxf(fmaxf(red[0], red[1]), fmaxf(red[2], red[3]));
    __syncthreads();
    float sm = 0.f;
    for (int c = tid; c < Qn; c += 256) sm += __expf(srow[c] - mx);
#pragma unroll
    for (int o = 32; o > 0; o >>= 1) sm += __shfl_xor(sm, o);
    if ((tid & 63) == 0) red[tid >> 6] = sm;
    __syncthreads();
    float inv = 1.f / (red[0] + red[1] + red[2] + red[3]);
    for (int c = tid; c < 520; c += 256)
        INITD[c] = (c < Qn) ? __expf(srow[c] - mx) * inv : 0.f;
}

__global__ void __launch_bounds__(256, 1)
hmm_fwd(const float* __restrict__ E, const unsigned* __restrict__ AMATh,
        const float* __restrict__ INITD, float* __restrict__ out,
        u64* __restrict__ fbuf)
{
    extern __shared__ char smem[];
    uint2* frag = (uint2*)(smem + L_FRAG);                    // [NT*KT*64]
    unsigned short* ustage0 = (unsigned short*)(smem + L_UST);// [NCH][16][USTR]

    const int tid  = threadIdx.x;
    const int lane = tid & 63;
    const int wv   = tid >> 6;
    const int bid  = blockIdx.x;
    const int g    = bid >> 3;       // group 0..15
    const int j    = bid & 7;        // producer slice
    const int q0   = j * NSL;

    // ---- one-time: pack A column-slice into LDS as MFMA B-fragments ----
    for (int f = tid; f < NT*KT*64; f += 256) {
        int tile = f >> 6, l = f & 63;
        int nt = tile / KT, kt = tile - nt*KT;
        int col = q0 + nt*16 + (l & 15);
        int kb  = kt*16 + ((l >> 4) << 2);
        unsigned h[4];
#pragma unroll
        for (int i = 0; i < 4; ++i) {
            int pk_ = kb + i;
            int jr = pk_ / 66, rr = pk_ - jr*66;
            unsigned hv = 0;
            if (rr < 65 && col < QP) {
                int qrow = jr*65 + rr;
                unsigned w = AMATh[(size_t)qrow*260 + (col >> 1)];
                hv = (col & 1) ? (w >> 16) : (w & 0xffffu);
            }
            h[i] = hv;
        }
        uint2 pk;
        pk.x = h[0] | (h[1] << 16);
        pk.y = h[2] | (h[3] << 16);
        frag[f] = pk;
    }
    for (int i = tid; i < NCH*(USTB/4); i += 256) ((u32t*)ustage0)[i] = 0u;
    __syncthreads();

    // ---- per-thread maps ----
    const int ntn  = (wv == 0) ? 2 : 1;
    const int nts0 = wv;
    int eoff[NCH][2][4];
#pragma unroll
    for (int c = 0; c < NCH; ++c) {
        int b0 = g*16 + c*8;
#pragma unroll
        for (int sl = 0; sl < 2; ++sl) {
#pragma unroll
            for (int r = 0; r < 4; ++r) {
                int nt  = sl ? 4 : nts0;
                int row = ((lane >> 4) << 2) + r;
                int col = nt*16 + (lane & 15);
                int q   = q0 + col;
                bool ok = (lane < 32) && (col < NSL) && (q < Qn) && (sl < ntn);
                eoff[c][sl][r] = ok ? ((b0 + row)*Qn + q) : -1;
            }
        }
    }
    const int rrow = tid >> 5;     // reader row 0..7
    const int t32  = tid & 31;
    const int nw   = (t32 < 8) ? 9 : 8;

    float llreg[NCH]; llreg[0] = 0.f; llreg[1] = 0.f;
    float lsr = 0.f;
    u64 w9[9];

    auto buf_base = [&](int slot, int c) {
        return fbuf + (size_t)(((slot*GR + g)*NCH + c)*8) * RW;
    };

    // ---- poll+read u_{s-1} of chain c (tag s, slot (s-1)&1); returns 1/sum ----
    auto poll_read = [&](int s, int c) -> float {
        const unsigned want = (unsigned)s;
        const u64* pb = buf_base((s-1) & 1, c) + (size_t)rrow*RW;
        unsigned pend = (t32 < 8) ? 0x1FFu : 0xFFu;
        while (pend) {
#pragma unroll
            for (int k = 0; k < 9; ++k) if (pend & (1u << k)) {
                int wi = (k < 8) ? (t32 + 32*k) : (256 + t32);
                w9[k] = __hip_atomic_load(&pb[wi], __ATOMIC_RELAXED, __HIP_MEMORY_SCOPE_AGENT);
            }
#pragma unroll
            for (int k = 0; k < 9; ++k)
                if ((pend & (1u << k)) && (unsigned)(w9[k] >> 32) == want) pend &= ~(1u << k);
        }
        float sum = 0.f;
#pragma unroll
        for (int k = 0; k < 9; ++k) if (k < nw) { u32t pr = (u32t)w9[k]; sum += bflo(pr) + bfhi(pr); }
#pragma unroll
        for (int o = 1; o < 32; o <<= 1) sum += __shfl_xor(sum, o);
        lsr = __logf(sum);
        llreg[c] += lsr;
        return 1.f / sum;
    };

    auto stage = [&](float iv, int c) {
        u32t* us32 = (u32t*)(ustage0) + c*(USTB/4) + rrow*(USTR/2);
#pragma unroll
        for (int k = 0; k < 9; ++k) if (k < nw) {
            int wi = (k < 8) ? (t32 + 32*k) : (256 + t32);
            u32t pr = (u32t)w9[k];
            us32[wi] = bfbits(bflo(pr)*iv) | (bfbits(bfhi(pr)*iv) << 16);
        }
    };

    auto emit_outputs = [&](int tOut, int c) {
        int brow = g*16 + c*8 + rrow;
        float* orow = out + ((size_t)brow*Tn + tOut)*OQ;
        if (t32 == 0 && j == 0) orow[Qn] = llreg[c];
#pragma unroll
        for (int k = 0; k < 9; ++k) if (k < nw) {
            int wi = (k < 8) ? (t32 + 32*k) : (256 + t32);
            u32t pr = (u32t)w9[k];
            int c0 = 2*wi;
#pragma unroll
            for (int h = 0; h < 2; ++h) {
                int cc = c0 + h;
                int jr = cc / 66, loc = cc - jr*66;
                if (jr == j && loc < 65) {
                    int q = q0 + loc;
                    if (q < Qn) orow[q] = __logf(h ? bfhi(pr) : bflo(pr)) - lsr;
                }
            }
        }
    };

    // ---- t = 0 : publish u0 for both chains (tag 1, slot 0) ----
#pragma unroll
    for (int c = 0; c < NCH; ++c) {
        u64* pp = buf_base(0, c);
        int b0 = g*16 + c*8;
        for (int p = tid; p < 264; p += 256) {
            int row = p/33, c2 = p - row*33;
            int lc0 = 2*c2, lc1 = lc0 + 1;
            float v0 = 0.f, v1 = 0.f;
            int qa = q0 + lc0, qb = q0 + lc1;
            if (lc0 < 65 && qa < Qn) v0 = fmaxf(E[(size_t)(b0+row)*Qn + qa], EPSc) * fmaxf(INITD[qa], EPSc);
            if (lc1 < 65 && qb < Qn) v1 = fmaxf(E[(size_t)(b0+row)*Qn + qb], EPSc) * fmaxf(INITD[qb], EPSc);
            u64 word = (u64)(bfbits(v0) | (bfbits(v1) << 16)) | ((u64)1u << 32);
            __hip_atomic_store(&pp[(size_t)row*RW + j*33 + c2], word,
                               __ATOMIC_RELAXED, __HIP_MEMORY_SCOPE_AGENT);
        }
    }

    // ---- main loop: two chains interleaved (each hides the other's exchange) ----
    for (int s = 1; s < Tn; ++s) {
        // prefetch E_s for both chains (HBM latency hides under polls)
        float ev[NCH][2][4];
        size_t ebase = (size_t)s * Bn * Qn;
#pragma unroll
        for (int c = 0; c < NCH; ++c)
#pragma unroll
            for (int sl = 0; sl < 2; ++sl)
#pragma unroll
                for (int r = 0; r < 4; ++r)
                    ev[c][sl][r] = (eoff[c][sl][r] >= 0) ? E[ebase + eoff[c][sl][r]] : 0.f;

#pragma unroll
        for (int c = 0; c < NCH; ++c) {
            float iv = poll_read(s, c);
            stage(iv, c);
            __syncthreads();    // ustage[c] visible; also fences prior round's MFMA reads

            f32x4 a0a = {0.f,0.f,0.f,0.f}, a0b = {0.f,0.f,0.f,0.f};
            f32x4 a1a = {0.f,0.f,0.f,0.f}, a1b = {0.f,0.f,0.f,0.f};
            {
                const unsigned short* urow = ustage0 + c*(USTB/2)
                                           + (lane & 15)*USTR + ((lane >> 4) << 2);
                const uint2* f0 = frag + (size_t)(nts0*KT)*64 + lane;
                const uint2* f1 = frag + (size_t)(4*KT)*64 + lane;
#pragma unroll 2
                for (int kt = 0; kt < KTA; ++kt) {
                    s16x4 af = __builtin_bit_cast(s16x4, *(const uint2*)(urow + kt*16));
                    a0a = __builtin_amdgcn_mfma_f32_16x16x16bf16_1k(af, __builtin_bit_cast(s16x4, f0[kt*64]), a0a, 0, 0, 0);
                    if (ntn == 2)
                        a1a = __builtin_amdgcn_mfma_f32_16x16x16bf16_1k(af, __builtin_bit_cast(s16x4, f1[kt*64]), a1a, 0, 0, 0);
                    int k2 = kt + KTA;
                    if (k2 < KT) {
                        s16x4 af2 = __builtin_bit_cast(s16x4, *(const uint2*)(urow + k2*16));
                        a0b = __builtin_amdgcn_mfma_f32_16x16x16bf16_1k(af2, __builtin_bit_cast(s16x4, f0[k2*64]), a0b, 0, 0, 0);
                        if (ntn == 2)
                            a1b = __builtin_amdgcn_mfma_f32_16x16x16bf16_1k(af2, __builtin_bit_cast(s16x4, f1[k2*64]), a1b, 0, 0, 0);
                    }
                }
            }

            // epilogue: u_s = max(E,eps)*max(R,eps) -> tagged (bf16pair|s+1) stores
            {
                u64 tagw = ((u64)(unsigned)(s + 1)) << 32;
                u64* pp = buf_base(s & 1, c);
                if (lane < 32) {
#pragma unroll
                    for (int r = 0; r < 4; ++r) {
                        int row = ((lane >> 4) << 2) + r;
                        {
                            int colLoc = nts0*16 + (lane & 15);
                            float R = fmaxf(a0a[r] + a0b[r], EPSc);
                            int q = q0 + colLoc;
                            float uv = (q < Qn) ? fmaxf(ev[c][0][r], EPSc) * R : 0.f;
                            float uvn = __shfl_xor(uv, 1);
                            if (!(lane & 1)) {
                                int c2 = colLoc >> 1;
                                u64 word = (u64)(bfbits(uv) | (bfbits(uvn) << 16)) | tagw;
                                __hip_atomic_store(&pp[(size_t)row*RW + j*33 + c2], word,
                                                   __ATOMIC_RELAXED, __HIP_MEMORY_SCOPE_AGENT);
                            }
                        }
                        if (ntn == 2 && (lane & 15) == 0) {
                            float R4 = fmaxf(a1a[r] + a1b[r], EPSc);
                            int q4 = q0 + 64;
                            float uv4 = (q4 < Qn) ? fmaxf(ev[c][1][r], EPSc) * R4 : 0.f;
                            u64 word = (u64)bfbits(uv4) | tagw;
                            __hip_atomic_store(&pp[(size_t)row*RW + j*33 + 32], word,
                                               __ATOMIC_RELAXED, __HIP_MEMORY_SCOPE_AGENT);
                        }
                    }
                }
            }
            emit_outputs(s - 1, c);   // off the inter-block critical path
        }
    }

    // ---- tail: t = 511 for both chains ----
#pragma unroll
    for (int c = 0; c < NCH; ++c) {
        poll_read(Tn, c);
        emit_outputs(Tn - 1, c);
    }
}

extern "C" void kernel_launch(void* const* d_in, const int* in_sizes, int n_in,
                              void* d_out, int out_size, void* d_ws, size_t ws_size,
                              hipStream_t stream) {
    (void)in_sizes; (void)n_in; (void)out_size;
    if (ws_size < (size_t)WS_TOTAL) return;

    const float* E    = (const float*)d_in[0];
    const float* logA = (const float*)d_in[1];
    const float* il   = (const float*)d_in[2];
    float* out = (float*)d_out;
    char*  ws  = (char*)d_ws;

    unsigned* AMATh = (unsigned*)(ws + WS_AMATH);
    float*    INITD = (float*)(ws + WS_INIT);
    u64*      fbuf  = (u64*)(ws + WS_FBUF);

    // exchange tags must be zero at every launch/replay (kills cross-replay staleness)
    hipMemsetAsync(ws + WS_FBUF, 0, 1081344, stream);

    prep_A<<<544, 256, 0, stream>>>(logA, AMATh);
    prep_init<<<1, 256, 0, stream>>>(il, INITD);

    static_assert(LDS_TOTAL < 160*1024, "LDS budget");
    hipFuncSetAttribute(reinterpret_cast<const void*>(hmm_fwd),
                        hipFuncAttributeMaxDynamicSharedMemorySize, LDS_TOTAL);
    hmm_fwd<<<GR*NBLK, 256, LDS_TOTAL, stream>>>(E, AMATh, INITD, out, fbuf);
}

// Round 10
// 2944.457 us; speedup vs baseline: 2.1221x; 2.1221x over previous
//
#include <hip/hip_runtime.h>
#include <cstdint>

typedef unsigned u32t;
typedef unsigned long long u64;
typedef float f32x4 __attribute__((ext_vector_type(4)));
typedef short s16x4 __attribute__((ext_vector_type(4)));

#define Qn   515
#define QP   520
#define Bn   256
#define Tn   512
#define OQ   516
#define EPSc 1e-16f
#define NSL  65           // real cols per block slice
#define NT   5            // 16-wide n tiles per slice
#define KT   33           // k tiles over padded k space (528/16)
#define KTA  17           // split-K first chunk
#define USTR 532          // ushorts per ustage row (zero-conflict)
#define NGRP 32
#define NBLK 8
#define RW   264          // u64 exchange words per row (bf16-pair | tag)

// workspace layout (bytes)
#define WS_AMATH 0                            // 544*260*4 = 565,760
#define WS_INIT  565760                       // pad to 568,320
#define WS_FBUF  568320                       // 2*32*8*264*8 = 1,081,344
#define WS_TOTAL (WS_FBUF + 1081344)

// LDS layout (bytes)
#define L_FRAG 0
#define L_UST  (NT*KT*64*8)                   // 84,480
#define L_INV  (L_UST + 16*USTR*2)            // +17,024 = 101,504
#define LDS_TOTAL (L_INV + 64)                // 101,568 -> 1 block/CU

__device__ __forceinline__ unsigned bfbits(float x) {
    unsigned u = __builtin_bit_cast(unsigned, x);
    unsigned r = u + 0x7FFFu + ((u >> 16) & 1u);
    return r >> 16;
}
__device__ __forceinline__ float bflo(u32t w) { return __builtin_bit_cast(float, w << 16); }
__device__ __forceinline__ float bfhi(u32t w) { return __builtin_bit_cast(float, w & 0xffff0000u); }

__global__ void prep_A(const float* __restrict__ logA, unsigned* __restrict__ AMATh) {
    __shared__ float red[4];
    __shared__ float srow[Qn];
    int row = blockIdx.x, tid = threadIdx.x;
    if (row >= Qn) {
        for (int c = tid; c < 260; c += 256) AMATh[(size_t)row*260 + c] = 0u;
        return;
    }
    float mx = -1e30f;
    for (int c = tid; c < Qn; c += 256) { float x = logA[(size_t)row*Qn + c]; srow[c] = x; mx = fmaxf(mx, x); }
#pragma unroll
    for (int o = 32; o > 0; o >>= 1) mx = fmaxf(mx, __shfl_xor(mx, o));
    if ((tid & 63) == 0) red[tid >> 6] = mx;
    __syncthreads();
    mx = fmaxf(fmaxf(red[0], red[1]), fmaxf(red[2], red[3]));
    __syncthreads();
    float sm = 0.f;
    for (int c = tid; c < Qn; c += 256) sm += __expf(srow[c] - mx);
#pragma unroll
    for (int o = 32; o > 0; o >>= 1) sm += __shfl_xor(sm, o);
    if ((tid & 63) == 0) red[tid >> 6] = sm;
    __syncthreads();
    float inv = 1.f / (red[0] + red[1] + red[2] + red[3]);
    for (int c2 = tid; c2 < 260; c2 += 256) {
        int c = 2*c2;
        float v0 = (c   < Qn) ? __expf(srow[c]   - mx) * inv : 0.f;
        float v1 = (c+1 < Qn) ? __expf(srow[c+1] - mx) * inv : 0.f;
        AMATh[(size_t)row*260 + c2] = bfbits(v0) | (bfbits(v1) << 16);
    }
}

__global__ void prep_init(const float* __restrict__ il, float* __restrict__ INITD) {
    __shared__ float red[4];
    __shared__ float srow[Qn];
    int tid = threadIdx.x;
    float mx = -1e30f;
    for (int c = tid; c < Qn; c += 256) { float x = il[c]; srow[c] = x; mx = fmaxf(mx, x); }
#pragma unroll
    for (int o = 32; o > 0; o >>= 1) mx = fmaxf(mx, __shfl_xor(mx, o));
    if ((tid & 63) == 0) red[tid >> 6] = mx;
    __syncthreads();
    mx = fmaxf(fmaxf(red[0], red[1]), fmaxf(red[2], red[3]));
    __syncthreads();
    float sm = 0.f;
    for (int c = tid; c < Qn; c += 256) sm += __expf(srow[c] - mx);
#pragma unroll
    for (int o = 32; o > 0; o >>= 1) sm += __shfl_xor(sm, o);
    if ((tid & 63) == 0) red[tid >> 6] = sm;
    __syncthreads();
    float inv = 1.f / (red[0] + red[1] + red[2] + red[3]);
    for (int c = tid; c < 520; c += 256)
        INITD[c] = (c < Qn) ? __expf(srow[c] - mx) * inv : 0.f;
}

__global__ void __launch_bounds__(256, 1)
hmm_fwd(const float* __restrict__ E, const unsigned* __restrict__ AMATh,
        const float* __restrict__ INITD, float* __restrict__ out,
        u64* __restrict__ fbuf)
{
    extern __shared__ char smem[];
    uint2* frag = (uint2*)(smem + L_FRAG);                    // [NT*KT*64]
    unsigned short* ustage = (unsigned short*)(smem + L_UST); // [16][USTR]
    u32t* ustage32 = (u32t*)ustage;
    float* invs = (float*)(smem + L_INV);                     // [8]

    const int tid  = threadIdx.x;
    const int lane = tid & 63;
    const int wv   = tid >> 6;
    const int bid  = blockIdx.x;
    const int g    = bid & 31;
    const int j    = bid >> 5;
    const int b0   = g * 8;
    const int q0   = j * NSL;

    // ---- one-time: pack A column-slice into LDS as MFMA B-fragments ----
    for (int f = tid; f < NT*KT*64; f += 256) {
        int tile = f >> 6, l = f & 63;
        int nt = tile / KT, kt = tile - nt*KT;
        int col = q0 + nt*16 + (l & 15);
        int kb  = kt*16 + ((l >> 4) << 2);
        unsigned h[4];
#pragma unroll
        for (int i = 0; i < 4; ++i) {
            int pk_ = kb + i;
            int jr = pk_ / 66, rr = pk_ - jr*66;
            unsigned hv = 0;
            if (rr < 65 && col < QP) {
                int qrow = jr*65 + rr;
                unsigned w = AMATh[(size_t)qrow*260 + (col >> 1)];
                hv = (col & 1) ? (w >> 16) : (w & 0xffffu);
            }
            h[i] = hv;
        }
        uint2 pk;
        pk.x = h[0] | (h[1] << 16);
        pk.y = h[2] | (h[3] << 16);
        frag[f] = pk;
    }
    for (int i = tid; i < 16*(USTR/2); i += 256) ustage32[i] = 0u;
    __syncthreads();

    // ---- per-thread maps ----
    const int ntn  = (wv == 0) ? 2 : 1;
    const int nts0 = wv;
    int eoff[2][4];
#pragma unroll
    for (int sl = 0; sl < 2; ++sl) {
#pragma unroll
        for (int r = 0; r < 4; ++r) {
            int nt  = sl ? 4 : nts0;
            int row = ((lane >> 4) << 2) + r;
            int col = nt*16 + (lane & 15);
            int q   = q0 + col;
            bool ok = (lane < 32) && (col < NSL) && (q < Qn) && (sl < ntn);
            eoff[sl][r] = ok ? ((b0 + row)*Qn + q) : -1;
        }
    }
    const int rrow = tid >> 5;     // reader row 0..7
    const int t32  = tid & 31;
    const int nw   = (t32 < 8) ? 9 : 8;

    float llreg = 0.f, lsr = 0.f;
    u64 w9[9];

    // ---- poll+read raw v_{s-1} (tag s, slot (s-1)&1), ping-pong 2 sets in flight ----
    auto poll_read = [&](int s) {
        const unsigned want = (unsigned)s;
        const u64* pb = fbuf + (((size_t)((s-1) & 1)*NGRP + g)*8 + rrow)*RW;
        unsigned pend = (t32 < 8) ? 0x1FFu : 0xFFu;
        u64 ta[9], tb[9];
        // prime set A
#pragma unroll
        for (int k = 0; k < 9; ++k) if (pend & (1u << k)) {
            int wi = (k < 8) ? (t32 + 32*k) : (256 + t32);
            ta[k] = __hip_atomic_load(&pb[wi], __ATOMIC_RELAXED, __HIP_MEMORY_SCOPE_AGENT);
        }
        while (pend) {
            unsigned pa = pend;
#pragma unroll
            for (int k = 0; k < 9; ++k) if (pend & (1u << k)) {     // issue set B
                int wi = (k < 8) ? (t32 + 32*k) : (256 + t32);
                tb[k] = __hip_atomic_load(&pb[wi], __ATOMIC_RELAXED, __HIP_MEMORY_SCOPE_AGENT);
            }
#pragma unroll
            for (int k = 0; k < 9; ++k)                              // check set A
                if ((pa & (1u << k)) && (unsigned)(ta[k] >> 32) == want) { w9[k] = ta[k]; pend &= ~(1u << k); }
            if (!pend) break;
            unsigned pbm = pend;
#pragma unroll
            for (int k = 0; k < 9; ++k) if (pend & (1u << k)) {     // issue set A
                int wi = (k < 8) ? (t32 + 32*k) : (256 + t32);
                ta[k] = __hip_atomic_load(&pb[wi], __ATOMIC_RELAXED, __HIP_MEMORY_SCOPE_AGENT);
            }
#pragma unroll
            for (int k = 0; k < 9; ++k)                              // check set B
                if ((pbm & (1u << k)) && (unsigned)(tb[k] >> 32) == want) { w9[k] = tb[k]; pend &= ~(1u << k); }
        }
        // sigma = row sum of raw v (normalization deferred to epilogue)
        float sum = 0.f;
#pragma unroll
        for (int k = 0; k < 9; ++k) if (k < nw) { u32t pr = (u32t)w9[k]; sum += bflo(pr) + bfhi(pr); }
#pragma unroll
        for (int o = 1; o < 32; o <<= 1) sum += __shfl_xor(sum, o);
        lsr = __logf(sum);
        llreg += lsr;
        if (t32 == 0) invs[rrow] = 1.f / sum;
    };

    auto stage_copy = [&]() {       // raw bf16 pairs -> ustage (no math)
        u32t* us32 = ustage32 + rrow*(USTR/2);
#pragma unroll
        for (int k = 0; k < 9; ++k) if (k < nw) {
            int wi = (k < 8) ? (t32 + 32*k) : (256 + t32);
            us32[wi] = (u32t)w9[k];
        }
    };

    auto emit_outputs = [&](int tOut) {
        if (t32 == 0 && j == 0)
            out[((size_t)(b0 + rrow)*Tn + tOut)*OQ + Qn] = llreg;
        float* orow = out + ((size_t)(b0 + rrow)*Tn + tOut)*OQ;
#pragma unroll
        for (int k = 0; k < 9; ++k) if (k < nw) {
            int wi = (k < 8) ? (t32 + 32*k) : (256 + t32);
            u32t pr = (u32t)w9[k];
            int c0 = 2*wi;
#pragma unroll
            for (int h = 0; h < 2; ++h) {
                int cc = c0 + h;
                int jr = cc / 66, loc = cc - jr*66;
                if (jr == j && loc < 65) {
                    int q = q0 + loc;
                    if (q < Qn) orow[q] = __logf(h ? bfhi(pr) : bflo(pr)) - lsr;
                }
            }
        }
    };

    // ---- t = 0 : publish raw v0 = max(E0,eps)*max(init,eps), tag 1, slot 0 ----
    {
        u64* pp = fbuf + ((size_t)0*NGRP + g)*(8*RW);
        for (int p = tid; p < 264; p += 256) {
            int row = p/33, c2 = p - row*33;
            int lc0 = 2*c2, lc1 = lc0 + 1;
            float v0 = 0.f, v1 = 0.f;
            int qa = q0 + lc0, qb = q0 + lc1;
            if (lc0 < 65 && qa < Qn) v0 = fmaxf(E[(size_t)(b0+row)*Qn + qa], EPSc) * fmaxf(INITD[qa], EPSc);
            if (lc1 < 65 && qb < Qn) v1 = fmaxf(E[(size_t)(b0+row)*Qn + qb], EPSc) * fmaxf(INITD[qb], EPSc);
            u64 word = (u64)(bfbits(v0) | (bfbits(v1) << 16)) | ((u64)1u << 32);
            __hip_atomic_store(&pp[(size_t)row*RW + j*33 + c2], word,
                               __ATOMIC_RELAXED, __HIP_MEMORY_SCOPE_AGENT);
        }
    }

    // ---- main loop ----
    for (int s = 1; s < Tn; ++s) {
        float ev[2][4];
        size_t ebase = (size_t)s * Bn * Qn;
#pragma unroll
        for (int sl = 0; sl < 2; ++sl)
#pragma unroll
            for (int r = 0; r < 4; ++r)
                ev[sl][r] = (eoff[sl][r] >= 0) ? E[ebase + eoff[sl][r]] : 0.f;

        poll_read(s);
        __syncthreads();            // prior MFMA's ustage reads done
        stage_copy();               // + invs[rrow] already written in poll_read
        __syncthreads();            // ustage + invs visible

        // MFMA: R' = v_{s-1} (16xK, rows 8..15 zero) @ Aslice, split-K x2 (unnormalized)
        f32x4 a0a = {0.f,0.f,0.f,0.f}, a0b = {0.f,0.f,0.f,0.f};
        f32x4 a1a = {0.f,0.f,0.f,0.f}, a1b = {0.f,0.f,0.f,0.f};
        {
            const unsigned short* urow = ustage + (lane & 15)*USTR + ((lane >> 4) << 2);
            const uint2* f0 = frag + (size_t)(nts0*KT)*64 + lane;
            const uint2* f1 = frag + (size_t)(4*KT)*64 + lane;
#pragma unroll 2
            for (int kt = 0; kt < KTA; ++kt) {
                s16x4 af = __builtin_bit_cast(s16x4, *(const uint2*)(urow + kt*16));
                a0a = __builtin_amdgcn_mfma_f32_16x16x16bf16_1k(af, __builtin_bit_cast(s16x4, f0[kt*64]), a0a, 0, 0, 0);
                if (ntn == 2)
                    a1a = __builtin_amdgcn_mfma_f32_16x16x16bf16_1k(af, __builtin_bit_cast(s16x4, f1[kt*64]), a1a, 0, 0, 0);
                int k2 = kt + KTA;
                if (k2 < KT) {
                    s16x4 af2 = __builtin_bit_cast(s16x4, *(const uint2*)(urow + k2*16));
                    a0b = __builtin_amdgcn_mfma_f32_16x16x16bf16_1k(af2, __builtin_bit_cast(s16x4, f0[k2*64]), a0b, 0, 0, 0);
                    if (ntn == 2)
                        a1b = __builtin_amdgcn_mfma_f32_16x16x16bf16_1k(af2, __builtin_bit_cast(s16x4, f1[k2*64]), a1b, 0, 0, 0);
                }
            }
        }

        // epilogue: R = max(R'/sigma, eps); v_s = max(E,eps)*R -> tagged bf16-pair stores
        {
            u64 tagw = ((u64)(unsigned)(s + 1)) << 32;
            u64* pp = fbuf + ((size_t)(s & 1)*NGRP + g)*(8*RW);
            if (lane < 32) {
#pragma unroll
                for (int r = 0; r < 4; ++r) {
                    int row = ((lane >> 4) << 2) + r;
                    float ivr = invs[row];
                    {
                        int colLoc = nts0*16 + (lane & 15);
                        float R = fmaxf((a0a[r] + a0b[r]) * ivr, EPSc);
                        int q = q0 + colLoc;
                        float uv = (q < Qn) ? fmaxf(ev[0][r], EPSc) * R : 0.f;
                        float uvn = __shfl_xor(uv, 1);
                        if (!(lane & 1)) {
                            int c2 = colLoc >> 1;
                            u64 word = (u64)(bfbits(uv) | (bfbits(uvn) << 16)) | tagw;
                            __hip_atomic_store(&pp[(size_t)row*RW + j*33 + c2], word,
                                               __ATOMIC_RELAXED, __HIP_MEMORY_SCOPE_AGENT);
                        }
                    }
                    if (ntn == 2 && (lane & 15) == 0) {
                        float R4 = fmaxf((a1a[r] + a1b[r]) * ivr, EPSc);
                        int q4 = q0 + 64;
                        float uv4 = (q4 < Qn) ? fmaxf(ev[1][r], EPSc) * R4 : 0.f;
                        u64 word = (u64)bfbits(uv4) | tagw;
                        __hip_atomic_store(&pp[(size_t)row*RW + j*33 + 32], word,
                                           __ATOMIC_RELAXED, __HIP_MEMORY_SCOPE_AGENT);
                    }
                }
            }
        }
        emit_outputs(s - 1);        // off the inter-block critical path
    }

    // ---- tail: t = 511 ----
    poll_read(Tn);
    emit_outputs(Tn - 1);
}

extern "C" void kernel_launch(void* const* d_in, const int* in_sizes, int n_in,
                              void* d_out, int out_size, void* d_ws, size_t ws_size,
                              hipStream_t stream) {
    (void)in_sizes; (void)n_in; (void)out_size;
    if (ws_size < (size_t)WS_TOTAL) return;

    const float* E    = (const float*)d_in[0];
    const float* logA = (const float*)d_in[1];
    const float* il   = (const float*)d_in[2];
    float* out = (float*)d_out;
    char*  ws  = (char*)d_ws;

    unsigned* AMATh = (unsigned*)(ws + WS_AMATH);
    float*    INITD = (float*)(ws + WS_INIT);
    u64*      fbuf  = (u64*)(ws + WS_FBUF);

    prep_A<<<544, 256, 0, stream>>>(logA, AMATh);
    prep_init<<<1, 256, 0, stream>>>(il, INITD);

    static_assert(LDS_TOTAL < 160*1024, "LDS budget");
    hipFuncSetAttribute(reinterpret_cast<const void*>(hmm_fwd),
                        hipFuncAttributeMaxDynamicSharedMemorySize, LDS_TOTAL);
    hmm_fwd<<<256, 256, LDS_TOTAL, stream>>>(E, AMATh, INITD, out, fbuf);
}